// Round 4
// baseline (2999.628 us; speedup 1.0000x reference)
//
#include <hip/hip_runtime.h>
#include <hip/hip_bf16.h>

// Problem constants (from reference)
#define Bq 256
#define Iq 64
#define Tq 16
#define Vq 4096
#define Eq 256
#define Hq 256
#define Gq 1024   // 4*H
#define HPAD 20   // hs row pad (80B, 16B-aligned)

__device__ __forceinline__ float sigf(float x) {
    return __builtin_amdgcn_rcpf(1.f + __expf(-x));
}
__device__ __forceinline__ float tanh_fast(float x) {
    float e = __expf(2.f * x);
    return 1.f - 2.f * __builtin_amdgcn_rcpf(e + 1.f);
}

// ---------------------------------------------------------------------------
// K0: gate-pack weights. W4[k][j] = float4(Wi[j,k], Wf[j,k], Wg[j,k], Wo[j,k])
// where original W is [1024][K] row-major with rows gate*256+j.
// Also packs biases: b4[j] = (b[j], b[j+256], b[j+512], b[j+768]).
__global__ void k_pack(const float* __restrict__ Wih_tok,
                       const float* __restrict__ Whh_tok,
                       const float* __restrict__ Wih_ins,
                       const float* __restrict__ Whh_ins,
                       const float* __restrict__ b_tok,
                       const float* __restrict__ b_ins,
                       float* __restrict__ Wih4t, float* __restrict__ Whh4t,
                       float* __restrict__ Wih4i, float* __restrict__ Whh4i,
                       float* __restrict__ b4t, float* __restrict__ b4i) {
    int g = blockIdx.x;          // 0..1023 original row
    int q = g >> 8;              // gate 0..3 (i,f,g,o)
    int j = g & 255;             // unit
    int k = threadIdx.x;         // 0..255
    int dst = (k * 256 + j) * 4 + q;
    Wih4t[dst] = Wih_tok[g * Hq + k];
    Whh4t[dst] = Whh_tok[g * Hq + k];
    Wih4i[dst] = Wih_ins[g * Hq + k];
    Whh4i[dst] = Whh_ins[g * Hq + k];
    if (k == 0) {
        b4t[j * 4 + q] = b_tok[g];
        b4i[j * 4 + q] = b_ins[g];
    }
}

// ---------------------------------------------------------------------------
// K1: Epre4[v][j] = float4 of 4 gate pre-activations: emb[v,:]·W + b  (incl bias)
// 512 blocks x 256 thr, 8 vocab rows/block.
__global__ __launch_bounds__(256) void k_epre(const float* __restrict__ emb,
                                              const float4* __restrict__ Wih4t,
                                              const float4* __restrict__ b4t,
                                              float4* __restrict__ Ep4) {
    __shared__ float es[8][Eq];
    int tid = threadIdx.x;
    int v0 = blockIdx.x * 8;
    #pragma unroll
    for (int r = 0; r < 8; ++r) es[r][tid] = emb[(v0 + r) * Eq + tid];
    __syncthreads();
    float4 a[8];
    #pragma unroll
    for (int r = 0; r < 8; ++r) a[r] = make_float4(0.f, 0.f, 0.f, 0.f);
    const float4* Wp = Wih4t + tid;
    #pragma unroll 2
    for (int k = 0; k < Eq; ++k) {
        float4 wv = Wp[k * 256];
        #pragma unroll
        for (int r = 0; r < 8; ++r) {
            float e = es[r][k];
            a[r].x += wv.x * e; a[r].y += wv.y * e;
            a[r].z += wv.z * e; a[r].w += wv.w * e;
        }
    }
    float4 b4 = b4t[tid];
    #pragma unroll
    for (int r = 0; r < 8; ++r) {
        Ep4[(size_t)(v0 + r) * 256 + tid] =
            make_float4(a[r].x + b4.x, a[r].y + b4.y, a[r].z + b4.z, a[r].w + b4.w);
    }
}

// ---------------------------------------------------------------------------
// K2: token-level LSTM, 16 seqs/block, 1024 blocks x 256 thr.
// launch_bounds(256,2): allow ~256 unified regs so the 64 accumulators live in
// ARCH VGPRs (R3 showed VGPR=64 + AGPR spill shuffle = +40% VALU insts).
#define FMAg(acc, ww, hv) \
    acc.x += (ww) * (hv).x; acc.y += (ww) * (hv).y; \
    acc.z += (ww) * (hv).z; acc.w += (ww) * (hv).w;

#define KSTEP(WPTR, kk) { \
    float4 wv = (WPTR)[(kk) * 256]; \
    const float4* hp = (const float4*)(&hs[kk][0]); \
    float4 h0 = hp[0], h1 = hp[1], h2 = hp[2], h3 = hp[3]; \
    FMAg(aI0, wv.x, h0) FMAg(aI1, wv.x, h1) FMAg(aI2, wv.x, h2) FMAg(aI3, wv.x, h3) \
    FMAg(aF0, wv.y, h0) FMAg(aF1, wv.y, h1) FMAg(aF2, wv.y, h2) FMAg(aF3, wv.y, h3) \
    FMAg(aG0, wv.z, h0) FMAg(aG1, wv.z, h1) FMAg(aG2, wv.z, h2) FMAg(aG3, wv.z, h3) \
    FMAg(aO0, wv.w, h0) FMAg(aO1, wv.w, h1) FMAg(aO2, wv.w, h2) FMAg(aO3, wv.w, h3) }

#define INITS(sg, mm, ss) { \
    float4 e = Ep4[(size_t)toks[ss][t] * 256 + tid]; \
    aI##sg.mm = e.x; aF##sg.mm = e.y; aG##sg.mm = e.z; aO##sg.mm = e.w; }

#define UPDS(sg, mm, ss) if (t < lens[ss]) { \
    float cn = sigf(aF##sg.mm) * c[ss] + sigf(aI##sg.mm) * tanh_fast(aG##sg.mm); \
    c[ss] = cn; \
    hs[tid][ss] = sigf(aO##sg.mm) * tanh_fast(cn); }

#define INITB(sg) { \
    aI##sg = make_float4(eb.x, eb.x, eb.x, eb.x); \
    aF##sg = make_float4(eb.y, eb.y, eb.y, eb.y); \
    aG##sg = make_float4(eb.z, eb.z, eb.z, eb.z); \
    aO##sg = make_float4(eb.w, eb.w, eb.w, eb.w); }

#define STXS(sg, mm, ss) \
    Xp4[(size_t)(s0 + ss) * 256 + tid] = \
        make_float4(aI##sg.mm, aF##sg.mm, aG##sg.mm, aO##sg.mm);

__global__ __launch_bounds__(256, 2) void k_token_lstm(
        const int* __restrict__ tokens,      // [16384][16]
        const int* __restrict__ tok_len,     // [16384]
        const float4* __restrict__ Ep4,      // [V*256] gate-packed (+bias)
        const float4* __restrict__ Whh4t,    // [256*256] gate-packed
        const float4* __restrict__ Wih4i,    // [256*256] gate-packed
        const float4* __restrict__ b4i,      // [256]
        float* __restrict__ instr_repr,      // [16384][256]
        float4* __restrict__ Xp4,            // [16384*256] or unused
        int do_xp) {
    __shared__ __align__(16) float hs[Hq][HPAD];
    __shared__ int toks[16][Tq];
    __shared__ int lens[16];
    int tid = threadIdx.x;
    int s0 = blockIdx.x * 16;

    #pragma unroll
    for (int s = 0; s < 16; ++s) hs[tid][s] = 0.f;
    toks[tid >> 4][tid & 15] = tokens[s0 * Tq + tid];
    if (tid < 16) lens[tid] = tok_len[s0 + tid];
    float c[16];
    #pragma unroll
    for (int s = 0; s < 16; ++s) c[s] = 0.f;
    __syncthreads();

    int tmax = 0;
    #pragma unroll
    for (int s = 0; s < 16; ++s) tmax = max(tmax, lens[s]);

    float4 aI0, aI1, aI2, aI3, aF0, aF1, aF2, aF3;
    float4 aG0, aG1, aG2, aG3, aO0, aO1, aO2, aO3;

    for (int t = 0; t < tmax; ++t) {
        // init accumulators from Epre gather (includes b_tok)
        INITS(0, x, 0)  INITS(0, y, 1)  INITS(0, z, 2)  INITS(0, w, 3)
        INITS(1, x, 4)  INITS(1, y, 5)  INITS(1, z, 6)  INITS(1, w, 7)
        INITS(2, x, 8)  INITS(2, y, 9)  INITS(2, z, 10) INITS(2, w, 11)
        INITS(3, x, 12) INITS(3, y, 13) INITS(3, z, 14) INITS(3, w, 15)
        const float4* Wp = Whh4t + tid;
        #pragma unroll 2
        for (int k = 0; k < Hq; ++k) { KSTEP(Wp, k) }
        __syncthreads();   // all done reading hs
        UPDS(0, x, 0)  UPDS(0, y, 1)  UPDS(0, z, 2)  UPDS(0, w, 3)
        UPDS(1, x, 4)  UPDS(1, y, 5)  UPDS(1, z, 6)  UPDS(1, w, 7)
        UPDS(2, x, 8)  UPDS(2, y, 9)  UPDS(2, z, 10) UPDS(2, w, 11)
        UPDS(3, x, 12) UPDS(3, y, 13) UPDS(3, z, 14) UPDS(3, w, 15)
        __syncthreads();   // hs visible for next step
    }

    #pragma unroll
    for (int s = 0; s < 16; ++s)
        instr_repr[(size_t)(s0 + s) * Hq + tid] = hs[tid][s];

    if (do_xp) {
        // Xp[seq] = Wih_ins · h_final + b_ins  (one extra k-pass)
        float4 eb = b4i[tid];
        INITB(0) INITB(1) INITB(2) INITB(3)
        const float4* Wp2 = Wih4i + tid;
        #pragma unroll 2
        for (int k = 0; k < Hq; ++k) { KSTEP(Wp2, k) }
        STXS(0, x, 0)  STXS(0, y, 1)  STXS(0, z, 2)  STXS(0, w, 3)
        STXS(1, x, 4)  STXS(1, y, 5)  STXS(1, z, 6)  STXS(1, w, 7)
        STXS(2, x, 8)  STXS(2, y, 9)  STXS(2, z, 10) STXS(2, w, 11)
        STXS(3, x, 12) STXS(3, y, 13) STXS(3, z, 14) STXS(3, w, 15)
    }
}

// ---------------------------------------------------------------------------
// K3 fast: instr LSTM, 128 blocks x 1024 thr, 2 seqs/block, K split 2-way.
// Weight stream (1MB/step) amortized over 2 seqs -> L2 traffic halved vs
// 1 seq/block. Thread (s=tid>>9, kg=(tid>>8)&1, j=tid&255): partial gate dot
// over k in [kg*128, kg*128+128); kg=1 writes partial to LDS; kg=0 combines,
// does the cell update. x-projection comes precomputed from Xp4 (incl b_ins).
__global__ __launch_bounds__(1024) void k_instr_lstm2(
        const float4* __restrict__ Xp4,        // [16384*256] gate-packed
        const int* __restrict__ instr_cnt,     // [256]
        const float4* __restrict__ Whh4i,      // [256*256] gate-packed
        const float* __restrict__ linW,        // [256]
        const float* __restrict__ linb,        // [1]
        float* __restrict__ out) {             // [256]
    __shared__ float hsl[2][Hq];
    __shared__ __align__(16) float4 part[2][Hq];
    __shared__ float red[16];
    int tid = threadIdx.x;
    int s  = tid >> 9;
    int kg = (tid >> 8) & 1;
    int j  = tid & 255;
    int b  = blockIdx.x * 2 + s;
    int len  = instr_cnt[b];
    int lmax = max(instr_cnt[blockIdx.x * 2], instr_cnt[blockIdx.x * 2 + 1]);
    if (kg == 0) hsl[s][j] = 0.f;
    float cc = 0.f;
    const float4* Wbase = Whh4i + kg * 128 * 256 + j;
    const float* hrow = &hsl[s][kg * 128];
    __syncthreads();

    for (int i = 0; i < lmax; ++i) {
        float4 acc = make_float4(0.f, 0.f, 0.f, 0.f);
        #pragma unroll 4
        for (int k = 0; k < 128; ++k) {
            float4 wv = Wbase[k * 256];
            float hv = hrow[k];
            acc.x += wv.x * hv; acc.y += wv.y * hv;
            acc.z += wv.z * hv; acc.w += wv.w * hv;
        }
        if (kg == 1) part[s][j] = acc;
        __syncthreads();
        if (kg == 0 && i < len) {
            float4 o = part[s][j];
            float4 xp = Xp4[((size_t)b * Iq + i) * 256 + j];
            float gi = acc.x + o.x + xp.x;
            float gf = acc.y + o.y + xp.y;
            float gg = acc.z + o.z + xp.z;
            float go = acc.w + o.w + xp.w;
            float cn = sigf(gf) * cc + sigf(gi) * tanh_fast(gg);
            cc = cn;
            hsl[s][j] = sigf(go) * tanh_fast(cn);
        }
        __syncthreads();
    }

    if (kg == 0) {
        float p = linW[j] * hsl[s][j];
        #pragma unroll
        for (int off = 32; off > 0; off >>= 1) p += __shfl_down(p, off);
        if ((tid & 63) == 0) red[tid >> 6] = p;
    }
    __syncthreads();
    if (tid < 2) {
        out[blockIdx.x * 2 + tid] =
            red[tid * 8] + red[tid * 8 + 1] + red[tid * 8 + 2] + red[tid * 8 + 3] + linb[0];
    }
}

// ---------------------------------------------------------------------------
// K3 fallback (no Xp4 workspace): 256 blocks x 256 thr, K=512 in-kernel.
__global__ __launch_bounds__(256) void k_instr_lstm(
        const float* __restrict__ instr_repr,  // [16384][256]
        const int* __restrict__ instr_cnt,     // [256]
        const float4* __restrict__ Wih4i,      // [256*256]
        const float4* __restrict__ Whh4i,      // [256*256]
        const float4* __restrict__ b4i,        // [256]
        const float* __restrict__ linW,        // [256]
        const float* __restrict__ linb,        // [1]
        float* __restrict__ out) {             // [256]
    __shared__ float hsl[Hq];
    __shared__ float xs[Hq];
    __shared__ float red[4];
    int tid = threadIdx.x;
    int b = blockIdx.x;
    int len = instr_cnt[b];
    hsl[tid] = 0.f;
    float cc = 0.f;
    float4 bb = b4i[tid];
    __syncthreads();

    for (int i = 0; i < len; ++i) {
        xs[tid] = instr_repr[((size_t)b * Iq + i) * Hq + tid];
        float4 acc = bb;
        __syncthreads();  // xs ready
        const float4* Wp = Wih4i + tid;
        #pragma unroll 4
        for (int k = 0; k < Hq; ++k) {
            float4 wv = Wp[k * 256];
            float xv = xs[k];
            acc.x += wv.x * xv; acc.y += wv.y * xv;
            acc.z += wv.z * xv; acc.w += wv.w * xv;
        }
        const float4* Wh = Whh4i + tid;
        #pragma unroll 4
        for (int k = 0; k < Hq; ++k) {
            float4 wv = Wh[k * 256];
            float hv = hsl[k];
            acc.x += wv.x * hv; acc.y += wv.y * hv;
            acc.z += wv.z * hv; acc.w += wv.w * hv;
        }
        __syncthreads();  // done reading hsl/xs
        float cn = sigf(acc.y) * cc + sigf(acc.x) * tanh_fast(acc.z);
        cc = cn;
        hsl[tid] = sigf(acc.w) * tanh_fast(cn);
        __syncthreads();  // hsl visible
    }

    float p = linW[tid] * hsl[tid];
    #pragma unroll
    for (int off = 32; off > 0; off >>= 1) p += __shfl_down(p, off);
    if ((tid & 63) == 0) red[tid >> 6] = p;
    __syncthreads();
    if (tid == 0) out[b] = red[0] + red[1] + red[2] + red[3] + linb[0];
}

// ---------------------------------------------------------------------------
extern "C" void kernel_launch(void* const* d_in, const int* in_sizes, int n_in,
                              void* d_out, int out_size, void* d_ws, size_t ws_size,
                              hipStream_t stream) {
    const int*   tokens  = (const int*)d_in[0];
    const int*   icnt    = (const int*)d_in[1];
    const int*   tcnt    = (const int*)d_in[2];
    const float* emb     = (const float*)d_in[3];
    const float* Wih_tok = (const float*)d_in[4];
    const float* Whh_tok = (const float*)d_in[5];
    const float* b_tok   = (const float*)d_in[6];
    const float* Wih_ins = (const float*)d_in[7];
    const float* Whh_ins = (const float*)d_in[8];
    const float* b_ins   = (const float*)d_in[9];
    const float* linW    = (const float*)d_in[10];
    const float* linb    = (const float*)d_in[11];
    float* out = (float*)d_out;

    float* ws = (float*)d_ws;
    // layout (floats)
    float* Wih4t = ws;                    // 262144
    float* Whh4t = Wih4t + 262144;        // 262144
    float* Wih4i = Whh4t + 262144;        // 262144
    float* Whh4i = Wih4i + 262144;        // 262144
    float* b4t   = Whh4i + 262144;        // 1024
    float* b4i   = b4t + 1024;            // 1024
    float* Ep4   = b4i + 1024;            // 4194304
    float* irepr = Ep4 + 4194304;         // 4194304
    float* Xp4   = irepr + 4194304;       // 16777216 (fast path only)

    size_t need_fb   = (size_t)(262144 * 4 + 2048 + 4194304 * 2) * 4;
    size_t need_fast = need_fb + (size_t)16777216 * 4;
    if (ws_size < need_fb) return;  // fail loudly
    int fast = (ws_size >= need_fast) ? 1 : 0;

    hipLaunchKernelGGL(k_pack, dim3(1024), dim3(256), 0, stream,
                       Wih_tok, Whh_tok, Wih_ins, Whh_ins, b_tok, b_ins,
                       Wih4t, Whh4t, Wih4i, Whh4i, b4t, b4i);
    hipLaunchKernelGGL(k_epre, dim3(512), dim3(256), 0, stream,
                       emb, (const float4*)Wih4t, (const float4*)b4t, (float4*)Ep4);
    hipLaunchKernelGGL(k_token_lstm, dim3(1024), dim3(256), 0, stream,
                       tokens, tcnt, (const float4*)Ep4, (const float4*)Whh4t,
                       (const float4*)Wih4i, (const float4*)b4i,
                       irepr, (float4*)Xp4, fast);
    if (fast) {
        hipLaunchKernelGGL(k_instr_lstm2, dim3(128), dim3(1024), 0, stream,
                           (const float4*)Xp4, icnt, (const float4*)Whh4i,
                           linW, linb, out);
    } else {
        hipLaunchKernelGGL(k_instr_lstm, dim3(256), dim3(256), 0, stream,
                           irepr, icnt, (const float4*)Wih4i, (const float4*)Whh4i,
                           (const float4*)b4i, linW, linb, out);
    }
}

// Round 5
// 2718.612 us; speedup vs baseline: 1.1034x; 1.1034x over previous
//
#include <hip/hip_runtime.h>
#include <hip/hip_bf16.h>

// Problem constants (from reference)
#define Bq 256
#define Iq 64
#define Tq 16
#define Vq 4096
#define Eq 256
#define Hq 256
#define Gq 1024   // 4*H

__device__ __forceinline__ float sigf(float x) {
    return __builtin_amdgcn_rcpf(1.f + __expf(-x));
}
__device__ __forceinline__ float tanh_fast(float x) {
    float e = __expf(2.f * x);
    return 1.f - 2.f * __builtin_amdgcn_rcpf(e + 1.f);
}

// ---------------------------------------------------------------------------
// K0: gate-pack weights. W4[k][j] = float4(Wi[j,k], Wf[j,k], Wg[j,k], Wo[j,k])
// Also packs biases: b4[j] = (b[j], b[j+256], b[j+512], b[j+768]).
__global__ void k_pack(const float* __restrict__ Wih_tok,
                       const float* __restrict__ Whh_tok,
                       const float* __restrict__ Wih_ins,
                       const float* __restrict__ Whh_ins,
                       const float* __restrict__ b_tok,
                       const float* __restrict__ b_ins,
                       float* __restrict__ Wih4t, float* __restrict__ Whh4t,
                       float* __restrict__ Wih4i, float* __restrict__ Whh4i,
                       float* __restrict__ b4t, float* __restrict__ b4i) {
    int g = blockIdx.x;          // 0..1023 original row
    int q = g >> 8;              // gate 0..3 (i,f,g,o)
    int j = g & 255;             // unit
    int k = threadIdx.x;         // 0..255
    int dst = (k * 256 + j) * 4 + q;
    Wih4t[dst] = Wih_tok[g * Hq + k];
    Whh4t[dst] = Whh_tok[g * Hq + k];
    Wih4i[dst] = Wih_ins[g * Hq + k];
    Whh4i[dst] = Whh_ins[g * Hq + k];
    if (k == 0) {
        b4t[j * 4 + q] = b_tok[g];
        b4i[j * 4 + q] = b_ins[g];
    }
}

// ---------------------------------------------------------------------------
// K1: Epre4[v][j] = float4 gate pre-activations: emb[v,:]·W + b_tok
__global__ __launch_bounds__(256) void k_epre(const float* __restrict__ emb,
                                              const float4* __restrict__ Wih4t,
                                              const float4* __restrict__ b4t,
                                              float4* __restrict__ Ep4) {
    __shared__ float es[8][Eq];
    int tid = threadIdx.x;
    int v0 = blockIdx.x * 8;
    #pragma unroll
    for (int r = 0; r < 8; ++r) es[r][tid] = emb[(v0 + r) * Eq + tid];
    __syncthreads();
    float4 a[8];
    #pragma unroll
    for (int r = 0; r < 8; ++r) a[r] = make_float4(0.f, 0.f, 0.f, 0.f);
    const float4* Wp = Wih4t + tid;
    #pragma unroll 2
    for (int k = 0; k < Eq; ++k) {
        float4 wv = Wp[k * 256];
        #pragma unroll
        for (int r = 0; r < 8; ++r) {
            float e = es[r][k];
            a[r].x += wv.x * e; a[r].y += wv.y * e;
            a[r].z += wv.z * e; a[r].w += wv.w * e;
        }
    }
    float4 b4 = b4t[tid];
    #pragma unroll
    for (int r = 0; r < 8; ++r) {
        Ep4[(size_t)(v0 + r) * 256 + tid] =
            make_float4(a[r].x + b4.x, a[r].y + b4.y, a[r].z + b4.z, a[r].w + b4.w);
    }
}

// ---------------------------------------------------------------------------
// K2: token-level LSTM, 8 seqs/block, 2048 blocks x 256 thr.
// Thread tid owns unit j=tid; acc = 8 named float4 (one per seq: gates ifgo).
// a[s] += w4 * h_s  -> 32 FMA per k with ONE dwordx4 weight load + 2 b128
// broadcasts. ~70 live VGPRs -> fits arch file (R3/R4: 64-acc tile went to
// AGPRs, +40% VALU).  Fused tail computes Xp = Wih_ins·h + b_ins.
#define FMA4(acc, wv4, hh) \
    acc.x += (wv4).x * (hh); acc.y += (wv4).y * (hh); \
    acc.z += (wv4).z * (hh); acc.w += (wv4).w * (hh);

#define KSTEP8(WPTR, kk) { \
    float4 wv = (WPTR)[(kk) * 256]; \
    const float4* hp = (const float4*)(&hs[kk][0]); \
    float4 hA = hp[0], hB = hp[1]; \
    FMA4(aS0, wv, hA.x) FMA4(aS1, wv, hA.y) FMA4(aS2, wv, hA.z) FMA4(aS3, wv, hA.w) \
    FMA4(aS4, wv, hB.x) FMA4(aS5, wv, hB.y) FMA4(aS6, wv, hB.z) FMA4(aS7, wv, hB.w) }

#define INIT8(ss) aS##ss = Ep4[(size_t)toks[ss][t] * 256 + tid];

#define UPD8(ss) if (t < lens[ss]) { \
    float cn = sigf(aS##ss.y) * c##ss + sigf(aS##ss.x) * tanh_fast(aS##ss.z); \
    c##ss = cn; \
    hs[tid][ss] = sigf(aS##ss.w) * tanh_fast(cn); }

#define STX8(ss) Xp4[(size_t)(s0 + ss) * 256 + tid] = aS##ss;

__global__ __launch_bounds__(256, 6) void k_token_lstm(
        const int* __restrict__ tokens,      // [16384][16]
        const int* __restrict__ tok_len,     // [16384]
        const float4* __restrict__ Ep4,      // [V*256] gate-packed (+b_tok)
        const float4* __restrict__ Whh4t,    // [256*256] gate-packed
        const float4* __restrict__ Wih4i,    // [256*256] gate-packed
        const float4* __restrict__ b4i,      // [256]
        float* __restrict__ instr_repr,      // [16384][256]
        float4* __restrict__ Xp4,            // [16384*256]
        int do_xp) {
    __shared__ __align__(16) float hs[Hq][8];
    __shared__ int toks[8][Tq];
    __shared__ int lens[8];
    int tid = threadIdx.x;
    int s0 = blockIdx.x * 8;

    #pragma unroll
    for (int s = 0; s < 8; ++s) hs[tid][s] = 0.f;
    if (tid < 128) toks[tid >> 4][tid & 15] = tokens[s0 * Tq + tid];
    if (tid < 8) lens[tid] = tok_len[s0 + tid];
    float c0 = 0.f, c1 = 0.f, c2 = 0.f, c3 = 0.f;
    float c4 = 0.f, c5 = 0.f, c6 = 0.f, c7 = 0.f;
    __syncthreads();

    int tmax = 0;
    #pragma unroll
    for (int s = 0; s < 8; ++s) tmax = max(tmax, lens[s]);

    float4 aS0, aS1, aS2, aS3, aS4, aS5, aS6, aS7;

    for (int t = 0; t < tmax; ++t) {
        INIT8(0) INIT8(1) INIT8(2) INIT8(3)
        INIT8(4) INIT8(5) INIT8(6) INIT8(7)
        const float4* Wp = Whh4t + tid;
        #pragma unroll 8
        for (int k = 0; k < Hq; ++k) { KSTEP8(Wp, k) }
        __syncthreads();   // all done reading hs
        UPD8(0) UPD8(1) UPD8(2) UPD8(3)
        UPD8(4) UPD8(5) UPD8(6) UPD8(7)
        __syncthreads();   // hs visible for next step
    }

    #pragma unroll
    for (int s = 0; s < 8; ++s)
        instr_repr[(size_t)(s0 + s) * Hq + tid] = hs[tid][s];

    if (do_xp) {
        float4 eb = b4i[tid];
        aS0 = eb; aS1 = eb; aS2 = eb; aS3 = eb;
        aS4 = eb; aS5 = eb; aS6 = eb; aS7 = eb;
        const float4* Wp2 = Wih4i + tid;
        #pragma unroll 8
        for (int k = 0; k < Hq; ++k) { KSTEP8(Wp2, k) }
        STX8(0) STX8(1) STX8(2) STX8(3)
        STX8(4) STX8(5) STX8(6) STX8(7)
    }
}

// ---------------------------------------------------------------------------
// K3 fast (R3 fused shape): 256 blocks x 256 thr, 1 seq/block, K=256.
// x-projection precomputed in Xp4 (incl b_ins); next-x prefetch; per-seq
// early exit. h read as float4 (4x fewer DS insts than scalar).
__global__ __launch_bounds__(256) void k_instr_fused(
        const float4* __restrict__ Xp4,        // [16384*256] gate-packed
        const int* __restrict__ instr_cnt,     // [256]
        const float4* __restrict__ Whh4i,      // [256*256] gate-packed
        const float* __restrict__ linW,        // [256]
        const float* __restrict__ linb,        // [1]
        float* __restrict__ out) {             // [256]
    __shared__ __align__(16) float hsl[Hq];
    __shared__ float red[4];
    int tid = threadIdx.x;
    int b = blockIdx.x;
    int len = instr_cnt[b];
    hsl[tid] = 0.f;
    float cc = 0.f;
    float4 xcur = Xp4[(size_t)b * Iq * 256 + tid];
    __syncthreads();

    for (int i = 0; i < len; ++i) {
        float4 acc = xcur;
        float4 xn = xcur;
        if (i + 1 < len) xn = Xp4[((size_t)b * Iq + i + 1) * 256 + tid];
        const float4* Wh = Whh4i + tid;
        const float4* hp = (const float4*)hsl;
        #pragma unroll 4
        for (int k4 = 0; k4 < Hq / 4; ++k4) {
            float4 h4 = hp[k4];
            float4 w0 = Wh[(k4 * 4 + 0) * 256];
            float4 w1 = Wh[(k4 * 4 + 1) * 256];
            float4 w2 = Wh[(k4 * 4 + 2) * 256];
            float4 w3 = Wh[(k4 * 4 + 3) * 256];
            FMA4(acc, w0, h4.x) FMA4(acc, w1, h4.y)
            FMA4(acc, w2, h4.z) FMA4(acc, w3, h4.w)
        }
        __syncthreads();  // done reading hsl
        float cn = sigf(acc.y) * cc + sigf(acc.x) * tanh_fast(acc.z);
        cc = cn;
        hsl[tid] = sigf(acc.w) * tanh_fast(cn);
        xcur = xn;
        __syncthreads();  // hsl visible
    }

    float p = linW[tid] * hsl[tid];
    #pragma unroll
    for (int off = 32; off > 0; off >>= 1) p += __shfl_down(p, off);
    if ((tid & 63) == 0) red[tid >> 6] = p;
    __syncthreads();
    if (tid == 0) out[b] = red[0] + red[1] + red[2] + red[3] + linb[0];
}

// ---------------------------------------------------------------------------
// K3 fallback (no Xp4 workspace): 256 blocks x 256 thr, K=512 in-kernel.
__global__ __launch_bounds__(256) void k_instr_lstm(
        const float* __restrict__ instr_repr,  // [16384][256]
        const int* __restrict__ instr_cnt,     // [256]
        const float4* __restrict__ Wih4i,      // [256*256]
        const float4* __restrict__ Whh4i,      // [256*256]
        const float4* __restrict__ b4i,        // [256]
        const float* __restrict__ linW,        // [256]
        const float* __restrict__ linb,        // [1]
        float* __restrict__ out) {             // [256]
    __shared__ float hsl[Hq];
    __shared__ float xs[Hq];
    __shared__ float red[4];
    int tid = threadIdx.x;
    int b = blockIdx.x;
    int len = instr_cnt[b];
    hsl[tid] = 0.f;
    float cc = 0.f;
    float4 bb = b4i[tid];
    __syncthreads();

    for (int i = 0; i < len; ++i) {
        xs[tid] = instr_repr[((size_t)b * Iq + i) * Hq + tid];
        float4 acc = bb;
        __syncthreads();
        const float4* Wp = Wih4i + tid;
        #pragma unroll 4
        for (int k = 0; k < Hq; ++k) {
            float4 wv = Wp[k * 256];
            float xv = xs[k];
            FMA4(acc, wv, xv)
        }
        const float4* Wh = Whh4i + tid;
        #pragma unroll 4
        for (int k = 0; k < Hq; ++k) {
            float4 wv = Wh[k * 256];
            float hv = hsl[k];
            FMA4(acc, wv, hv)
        }
        __syncthreads();
        float cn = sigf(acc.y) * cc + sigf(acc.x) * tanh_fast(acc.z);
        cc = cn;
        hsl[tid] = sigf(acc.w) * tanh_fast(cn);
        __syncthreads();
    }

    float p = linW[tid] * hsl[tid];
    #pragma unroll
    for (int off = 32; off > 0; off >>= 1) p += __shfl_down(p, off);
    if ((tid & 63) == 0) red[tid >> 6] = p;
    __syncthreads();
    if (tid == 0) out[b] = red[0] + red[1] + red[2] + red[3] + linb[0];
}

// ---------------------------------------------------------------------------
extern "C" void kernel_launch(void* const* d_in, const int* in_sizes, int n_in,
                              void* d_out, int out_size, void* d_ws, size_t ws_size,
                              hipStream_t stream) {
    const int*   tokens  = (const int*)d_in[0];
    const int*   icnt    = (const int*)d_in[1];
    const int*   tcnt    = (const int*)d_in[2];
    const float* emb     = (const float*)d_in[3];
    const float* Wih_tok = (const float*)d_in[4];
    const float* Whh_tok = (const float*)d_in[5];
    const float* b_tok   = (const float*)d_in[6];
    const float* Wih_ins = (const float*)d_in[7];
    const float* Whh_ins = (const float*)d_in[8];
    const float* b_ins   = (const float*)d_in[9];
    const float* linW    = (const float*)d_in[10];
    const float* linb    = (const float*)d_in[11];
    float* out = (float*)d_out;

    float* ws = (float*)d_ws;
    float* Wih4t = ws;                    // 262144
    float* Whh4t = Wih4t + 262144;        // 262144
    float* Wih4i = Whh4t + 262144;        // 262144
    float* Whh4i = Wih4i + 262144;        // 262144
    float* b4t   = Whh4i + 262144;        // 1024
    float* b4i   = b4t + 1024;            // 1024
    float* Ep4   = b4i + 1024;            // 4194304
    float* irepr = Ep4 + 4194304;         // 4194304
    float* Xp4   = irepr + 4194304;       // 16777216 (fast path only)

    size_t need_fb   = (size_t)(262144 * 4 + 2048 + 4194304 * 2) * 4;
    size_t need_fast = need_fb + (size_t)16777216 * 4;
    if (ws_size < need_fb) return;  // fail loudly
    int fast = (ws_size >= need_fast) ? 1 : 0;

    hipLaunchKernelGGL(k_pack, dim3(1024), dim3(256), 0, stream,
                       Wih_tok, Whh_tok, Wih_ins, Whh_ins, b_tok, b_ins,
                       Wih4t, Whh4t, Wih4i, Whh4i, b4t, b4i);
    hipLaunchKernelGGL(k_epre, dim3(512), dim3(256), 0, stream,
                       emb, (const float4*)Wih4t, (const float4*)b4t, (float4*)Ep4);
    hipLaunchKernelGGL(k_token_lstm, dim3(2048), dim3(256), 0, stream,
                       tokens, tcnt, (const float4*)Ep4, (const float4*)Whh4t,
                       (const float4*)Wih4i, (const float4*)b4i,
                       irepr, (float4*)Xp4, fast);
    if (fast) {
        hipLaunchKernelGGL(k_instr_fused, dim3(256), dim3(256), 0, stream,
                           (const float4*)Xp4, icnt, (const float4*)Whh4i,
                           linW, linb, out);
    } else {
        hipLaunchKernelGGL(k_instr_lstm, dim3(256), dim3(256), 0, stream,
                           irepr, icnt, (const float4*)Wih4i, (const float4*)Whh4i,
                           (const float4*)b4i, linW, linb, out);
    }
}

// Round 6
// 1826.260 us; speedup vs baseline: 1.6425x; 1.4886x over previous
//
#include <hip/hip_runtime.h>
#include <hip/hip_bf16.h>

// Problem constants (from reference)
#define Bq 256
#define Iq 64
#define Tq 16
#define Vq 4096
#define Eq 256
#define Hq 256
#define Gq 1024   // 4*H
#define NSEQ 16384

__device__ __forceinline__ float sigf(float x) {
    return __builtin_amdgcn_rcpf(1.f + __expf(-x));
}
__device__ __forceinline__ float tanh_fast(float x) {
    float e = __expf(2.f * x);
    return 1.f - 2.f * __builtin_amdgcn_rcpf(e + 1.f);
}

// ---------------------------------------------------------------------------
// K0: gate-pack weights. W4[k][j] = float4(Wi[j,k], Wf[j,k], Wg[j,k], Wo[j,k])
__global__ void k_pack(const float* __restrict__ Wih_tok,
                       const float* __restrict__ Whh_tok,
                       const float* __restrict__ Wih_ins,
                       const float* __restrict__ Whh_ins,
                       const float* __restrict__ b_tok,
                       const float* __restrict__ b_ins,
                       float* __restrict__ Wih4t, float* __restrict__ Whh4t,
                       float* __restrict__ Wih4i, float* __restrict__ Whh4i,
                       float* __restrict__ b4t, float* __restrict__ b4i) {
    int g = blockIdx.x;          // 0..1023 original row
    int q = g >> 8;              // gate 0..3 (i,f,g,o)
    int j = g & 255;             // unit
    int k = threadIdx.x;         // 0..255
    int dst = (k * 256 + j) * 4 + q;
    Wih4t[dst] = Wih_tok[g * Hq + k];
    Whh4t[dst] = Whh_tok[g * Hq + k];
    Wih4i[dst] = Wih_ins[g * Hq + k];
    Whh4i[dst] = Whh_ins[g * Hq + k];
    if (k == 0) {
        b4t[j * 4 + q] = b_tok[g];
        b4i[j * 4 + q] = b_ins[g];
    }
}

// ---------------------------------------------------------------------------
// K0b: counting sort of seq ids by token length (17 bins). Single block.
// Any intra-bin order is valid; blocks of 8 sorted seqs get uniform tmax
// (E[steps] 14.2 -> 8.1, a 1.76x work cut in k_token_lstm).
__global__ __launch_bounds__(1024) void k_sort(const int* __restrict__ tok_len,
                                               int* __restrict__ perm) {
    __shared__ int cnt[17];
    __shared__ int base[17];
    int tid = threadIdx.x;
    if (tid < 17) cnt[tid] = 0;
    __syncthreads();
    for (int i = tid; i < NSEQ; i += 1024) atomicAdd(&cnt[tok_len[i]], 1);
    __syncthreads();
    if (tid == 0) {
        int acc = 0;
        for (int b = 0; b < 17; ++b) { base[b] = acc; acc += cnt[b]; }
    }
    __syncthreads();
    for (int i = tid; i < NSEQ; i += 1024) {
        int pos = atomicAdd(&base[tok_len[i]], 1);
        perm[pos] = i;
    }
}

// ---------------------------------------------------------------------------
// K1: Epre4[v][j] = float4 gate pre-activations: emb[v,:]·W + b_tok
__global__ __launch_bounds__(256) void k_epre(const float* __restrict__ emb,
                                              const float4* __restrict__ Wih4t,
                                              const float4* __restrict__ b4t,
                                              float4* __restrict__ Ep4) {
    __shared__ float es[8][Eq];
    int tid = threadIdx.x;
    int v0 = blockIdx.x * 8;
    #pragma unroll
    for (int r = 0; r < 8; ++r) es[r][tid] = emb[(v0 + r) * Eq + tid];
    __syncthreads();
    float4 a[8];
    #pragma unroll
    for (int r = 0; r < 8; ++r) a[r] = make_float4(0.f, 0.f, 0.f, 0.f);
    const float4* Wp = Wih4t + tid;
    #pragma unroll 2
    for (int k = 0; k < Eq; ++k) {
        float4 wv = Wp[k * 256];
        #pragma unroll
        for (int r = 0; r < 8; ++r) {
            float e = es[r][k];
            a[r].x += wv.x * e; a[r].y += wv.y * e;
            a[r].z += wv.z * e; a[r].w += wv.w * e;
        }
    }
    float4 b4 = b4t[tid];
    #pragma unroll
    for (int r = 0; r < 8; ++r) {
        Ep4[(size_t)(v0 + r) * 256 + tid] =
            make_float4(a[r].x + b4.x, a[r].y + b4.y, a[r].z + b4.z, a[r].w + b4.w);
    }
}

// ---------------------------------------------------------------------------
// K2: token-level LSTM, 8 length-sorted seqs/block, 2048 blocks x 256 thr.
// Plain launch_bounds(256): 512-reg unified cap. R5's (256,6) caused scratch
// spills (VGPR=40, WRITE_SIZE 400MB); min-waves hints shrink the budget.
#define FMA4(acc, wv4, hh) \
    acc.x += (wv4).x * (hh); acc.y += (wv4).y * (hh); \
    acc.z += (wv4).z * (hh); acc.w += (wv4).w * (hh);

#define KSTEP8(WPTR, kk) { \
    float4 wv = (WPTR)[(kk) * 256]; \
    const float4* hp = (const float4*)(&hs[kk][0]); \
    float4 hA = hp[0], hB = hp[1]; \
    FMA4(aS0, wv, hA.x) FMA4(aS1, wv, hA.y) FMA4(aS2, wv, hA.z) FMA4(aS3, wv, hA.w) \
    FMA4(aS4, wv, hB.x) FMA4(aS5, wv, hB.y) FMA4(aS6, wv, hB.z) FMA4(aS7, wv, hB.w) }

#define INIT8(ss) aS##ss = Ep4[(size_t)toks[ss][t] * 256 + tid];

#define UPD8(ss) if (t < lens[ss]) { \
    float cn = sigf(aS##ss.y) * c##ss + sigf(aS##ss.x) * tanh_fast(aS##ss.z); \
    c##ss = cn; \
    hs[tid][ss] = sigf(aS##ss.w) * tanh_fast(cn); }

#define STX8(ss) Xp4[(size_t)sid[ss] * 256 + tid] = aS##ss;

__global__ __launch_bounds__(256) void k_token_lstm(
        const int* __restrict__ tokens,      // [16384][16]
        const int* __restrict__ tok_len,     // [16384]
        const int* __restrict__ perm,        // [16384] length-sorted seq ids
        const float4* __restrict__ Ep4,      // [V*256] gate-packed (+b_tok)
        const float4* __restrict__ Whh4t,    // [256*256] gate-packed
        const float4* __restrict__ Wih4i,    // [256*256] gate-packed
        const float4* __restrict__ b4i,      // [256]
        float* __restrict__ instr_repr,      // [16384][256]
        float4* __restrict__ Xp4,            // [16384*256]
        int do_xp) {
    __shared__ __align__(16) float hs[Hq][8];
    __shared__ int toks[8][Tq];
    __shared__ int lens[8];
    __shared__ int sid[8];
    int tid = threadIdx.x;
    int s0 = blockIdx.x * 8;

    if (tid < 8) {
        int q = perm[s0 + tid];
        sid[tid] = q;
        lens[tid] = tok_len[q];
    }
    #pragma unroll
    for (int s = 0; s < 8; ++s) hs[tid][s] = 0.f;
    __syncthreads();
    if (tid < 128) toks[tid >> 4][tid & 15] = tokens[sid[tid >> 4] * Tq + (tid & 15)];
    float c0 = 0.f, c1 = 0.f, c2 = 0.f, c3 = 0.f;
    float c4 = 0.f, c5 = 0.f, c6 = 0.f, c7 = 0.f;
    __syncthreads();

    int tmax = 0;
    #pragma unroll
    for (int s = 0; s < 8; ++s) tmax = max(tmax, lens[s]);

    float4 aS0, aS1, aS2, aS3, aS4, aS5, aS6, aS7;

    for (int t = 0; t < tmax; ++t) {
        INIT8(0) INIT8(1) INIT8(2) INIT8(3)
        INIT8(4) INIT8(5) INIT8(6) INIT8(7)
        const float4* Wp = Whh4t + tid;
        #pragma unroll 8
        for (int k = 0; k < Hq; ++k) { KSTEP8(Wp, k) }
        __syncthreads();   // all done reading hs
        UPD8(0) UPD8(1) UPD8(2) UPD8(3)
        UPD8(4) UPD8(5) UPD8(6) UPD8(7)
        __syncthreads();   // hs visible for next step
    }

    #pragma unroll
    for (int s = 0; s < 8; ++s)
        instr_repr[(size_t)sid[s] * Hq + tid] = hs[tid][s];

    if (do_xp) {
        float4 eb = b4i[tid];
        aS0 = eb; aS1 = eb; aS2 = eb; aS3 = eb;
        aS4 = eb; aS5 = eb; aS6 = eb; aS7 = eb;
        const float4* Wp2 = Wih4i + tid;
        #pragma unroll 8
        for (int k = 0; k < Hq; ++k) { KSTEP8(Wp2, k) }
        STX8(0) STX8(1) STX8(2) STX8(3)
        STX8(4) STX8(5) STX8(6) STX8(7)
    }
}

// ---------------------------------------------------------------------------
// K3 fast: 256 blocks x 256 thr, 1 seq/block, K=256, Xp4 precomputed (+b_ins).
__global__ __launch_bounds__(256) void k_instr_fused(
        const float4* __restrict__ Xp4,        // [16384*256] gate-packed
        const int* __restrict__ instr_cnt,     // [256]
        const float4* __restrict__ Whh4i,      // [256*256] gate-packed
        const float* __restrict__ linW,        // [256]
        const float* __restrict__ linb,        // [1]
        float* __restrict__ out) {             // [256]
    __shared__ __align__(16) float hsl[Hq];
    __shared__ float red[4];
    int tid = threadIdx.x;
    int b = blockIdx.x;
    int len = instr_cnt[b];
    hsl[tid] = 0.f;
    float cc = 0.f;
    float4 xcur = Xp4[(size_t)b * Iq * 256 + tid];
    __syncthreads();

    for (int i = 0; i < len; ++i) {
        float4 acc = xcur;
        float4 xn = xcur;
        if (i + 1 < len) xn = Xp4[((size_t)b * Iq + i + 1) * 256 + tid];
        const float4* Wh = Whh4i + tid;
        const float4* hp = (const float4*)hsl;
        #pragma unroll 4
        for (int k4 = 0; k4 < Hq / 4; ++k4) {
            float4 h4 = hp[k4];
            float4 w0 = Wh[(k4 * 4 + 0) * 256];
            float4 w1 = Wh[(k4 * 4 + 1) * 256];
            float4 w2 = Wh[(k4 * 4 + 2) * 256];
            float4 w3 = Wh[(k4 * 4 + 3) * 256];
            FMA4(acc, w0, h4.x) FMA4(acc, w1, h4.y)
            FMA4(acc, w2, h4.z) FMA4(acc, w3, h4.w)
        }
        __syncthreads();  // done reading hsl
        float cn = sigf(acc.y) * cc + sigf(acc.x) * tanh_fast(acc.z);
        cc = cn;
        hsl[tid] = sigf(acc.w) * tanh_fast(cn);
        xcur = xn;
        __syncthreads();  // hsl visible
    }

    float p = linW[tid] * hsl[tid];
    #pragma unroll
    for (int off = 32; off > 0; off >>= 1) p += __shfl_down(p, off);
    if ((tid & 63) == 0) red[tid >> 6] = p;
    __syncthreads();
    if (tid == 0) out[b] = red[0] + red[1] + red[2] + red[3] + linb[0];
}

// ---------------------------------------------------------------------------
// K3 fallback (no Xp4 workspace): 256 blocks x 256 thr, K=512 in-kernel.
__global__ __launch_bounds__(256) void k_instr_lstm(
        const float* __restrict__ instr_repr,  // [16384][256]
        const int* __restrict__ instr_cnt,     // [256]
        const float4* __restrict__ Wih4i,      // [256*256]
        const float4* __restrict__ Whh4i,      // [256*256]
        const float4* __restrict__ b4i,        // [256]
        const float* __restrict__ linW,        // [256]
        const float* __restrict__ linb,        // [1]
        float* __restrict__ out) {             // [256]
    __shared__ float hsl[Hq];
    __shared__ float xs[Hq];
    __shared__ float red[4];
    int tid = threadIdx.x;
    int b = blockIdx.x;
    int len = instr_cnt[b];
    hsl[tid] = 0.f;
    float cc = 0.f;
    float4 bb = b4i[tid];
    __syncthreads();

    for (int i = 0; i < len; ++i) {
        xs[tid] = instr_repr[((size_t)b * Iq + i) * Hq + tid];
        float4 acc = bb;
        __syncthreads();
        const float4* Wp = Wih4i + tid;
        #pragma unroll 4
        for (int k = 0; k < Hq; ++k) {
            float4 wv = Wp[k * 256];
            float xv = xs[k];
            FMA4(acc, wv, xv)
        }
        const float4* Wh = Whh4i + tid;
        #pragma unroll 4
        for (int k = 0; k < Hq; ++k) {
            float4 wv = Wh[k * 256];
            float hv = hsl[k];
            FMA4(acc, wv, hv)
        }
        __syncthreads();
        float cn = sigf(acc.y) * cc + sigf(acc.x) * tanh_fast(acc.z);
        cc = cn;
        hsl[tid] = sigf(acc.w) * tanh_fast(cn);
        __syncthreads();
    }

    float p = linW[tid] * hsl[tid];
    #pragma unroll
    for (int off = 32; off > 0; off >>= 1) p += __shfl_down(p, off);
    if ((tid & 63) == 0) red[tid >> 6] = p;
    __syncthreads();
    if (tid == 0) out[b] = red[0] + red[1] + red[2] + red[3] + linb[0];
}

// ---------------------------------------------------------------------------
extern "C" void kernel_launch(void* const* d_in, const int* in_sizes, int n_in,
                              void* d_out, int out_size, void* d_ws, size_t ws_size,
                              hipStream_t stream) {
    const int*   tokens  = (const int*)d_in[0];
    const int*   icnt    = (const int*)d_in[1];
    const int*   tcnt    = (const int*)d_in[2];
    const float* emb     = (const float*)d_in[3];
    const float* Wih_tok = (const float*)d_in[4];
    const float* Whh_tok = (const float*)d_in[5];
    const float* b_tok   = (const float*)d_in[6];
    const float* Wih_ins = (const float*)d_in[7];
    const float* Whh_ins = (const float*)d_in[8];
    const float* b_ins   = (const float*)d_in[9];
    const float* linW    = (const float*)d_in[10];
    const float* linb    = (const float*)d_in[11];
    float* out = (float*)d_out;

    float* ws = (float*)d_ws;
    float* Wih4t = ws;                    // 262144
    float* Whh4t = Wih4t + 262144;        // 262144
    float* Wih4i = Whh4t + 262144;        // 262144
    float* Whh4i = Wih4i + 262144;        // 262144
    float* b4t   = Whh4i + 262144;        // 1024
    float* b4i   = b4t + 1024;            // 1024
    int*   perm  = (int*)(b4i + 1024);    // 16384 (int)
    float* Ep4   = b4i + 1024 + 16384;    // 4194304
    float* irepr = Ep4 + 4194304;         // 4194304
    float* Xp4   = irepr + 4194304;       // 16777216 (fast path only)

    size_t need_fb   = (size_t)(262144 * 4 + 2048 + 16384 + 4194304 * 2) * 4;
    size_t need_fast = need_fb + (size_t)16777216 * 4;
    if (ws_size < need_fb) return;  // fail loudly
    int fast = (ws_size >= need_fast) ? 1 : 0;

    hipLaunchKernelGGL(k_pack, dim3(1024), dim3(256), 0, stream,
                       Wih_tok, Whh_tok, Wih_ins, Whh_ins, b_tok, b_ins,
                       Wih4t, Whh4t, Wih4i, Whh4i, b4t, b4i);
    hipLaunchKernelGGL(k_sort, dim3(1), dim3(1024), 0, stream, tcnt, perm);
    hipLaunchKernelGGL(k_epre, dim3(512), dim3(256), 0, stream,
                       emb, (const float4*)Wih4t, (const float4*)b4t, (float4*)Ep4);
    hipLaunchKernelGGL(k_token_lstm, dim3(2048), dim3(256), 0, stream,
                       tokens, tcnt, perm, (const float4*)Ep4, (const float4*)Whh4t,
                       (const float4*)Wih4i, (const float4*)b4i,
                       irepr, (float4*)Xp4, fast);
    if (fast) {
        hipLaunchKernelGGL(k_instr_fused, dim3(256), dim3(256), 0, stream,
                           (const float4*)Xp4, icnt, (const float4*)Whh4i,
                           linW, linb, out);
    } else {
        hipLaunchKernelGGL(k_instr_lstm, dim3(256), dim3(256), 0, stream,
                           irepr, icnt, (const float4*)Wih4i, (const float4*)Whh4i,
                           (const float4*)b4i, linW, linb, out);
    }
}